// Round 10
// baseline (32.759 us; speedup 1.0000x reference)
//
#include <hip/hip_runtime.h>

typedef _Float16 f16x8 __attribute__((ext_vector_type(8)));
typedef _Float16 f16x4 __attribute__((ext_vector_type(4)));
typedef float f32x4 __attribute__((ext_vector_type(4)));

#define B_N 8192
#define K_N 256
#define DIM_N 1024

// ---------------- prep_w: U=f16(Dinv-1), W=f16(-2c*Dinv) in MFMA-fragment-PACKED layout ----------------
// pk f16-index: ((cg*32 + kc)*64 + g*16 + cl)*8 + j  where class k=(cg*16+cl), dim d=(kc*32+g*8+j).
// A wave reading pk + (cg*32+kc)*512 + lane*8 gets exactly the B-fragment (col=lane&15, k=(lane>>4)*8+j).
// ec[k] = -0.5*(log_det + c2): softmax_k(-0.5*acc + ec) == reference resp (row-consts cancel).
__global__ __launch_bounds__(256) void prep_w(const float* __restrict__ Dm,
                                              const float* __restrict__ Cm,
                                              _Float16* __restrict__ Upk,
                                              _Float16* __restrict__ Wpk,
                                              float* __restrict__ ec) {
    const int k = blockIdx.x, t = threadIdx.x;
    const int d = t * 4;
    const float4 dv = *(const float4*)(Dm + (size_t)k * DIM_N + d);
    const float4 cv = *(const float4*)(Cm + (size_t)k * DIM_N + d);
    float dd[4] = {dv.x, dv.y, dv.z, dv.w};
    float cc[4] = {cv.x, cv.y, cv.z, cv.w};
    f16x4 uo, wo;
    float llog = 0.f, lc2 = 0.f;
#pragma unroll
    for (int i = 0; i < 4; ++i) {
        float da = fabsf(dd[i]) + 1e-4f;
        float dinv = 1.0f / da;
        llog += logf(da);
        lc2 += cc[i] * cc[i] * dinv;
        uo[i] = (_Float16)(dinv - 1.0f);
        wo[i] = (_Float16)(-2.0f * cc[i] * dinv);
    }
    const int cg = k >> 4, cl = k & 15;
    const int kc = d >> 5, g = (d >> 3) & 3, j0 = d & 7;
    const size_t off = ((size_t)(cg * 32 + kc) * 64 + g * 16 + cl) * 8 + j0;
    *(f16x4*)(Upk + off) = uo;
    *(f16x4*)(Wpk + off) = wo;
    float both = llog + lc2;
#pragma unroll
    for (int m = 1; m <= 32; m <<= 1) both += __shfl_xor(both, m, 64);
    __shared__ float sb[4];
    if ((t & 63) == 0) sb[t >> 6] = both;
    __syncthreads();
    if (t == 0) ec[k] = -0.5f * (sb[0] + sb[1] + sb[2] + sb[3]);
}

// ---------------- gmm_fused: 32 rows x 256 classes; 16 waves (1024 thr), wave-tile 32x16 ----------------
// Wave w owns classes w*16..w*16+15 (n1, m2, 2 products -> 8 MFMA/chunk-64).
// x f16 staged ONCE into 64KB LDS (4 quarters, 4 barriers total); x^2 computed in-register.
// B (U,W): register fragments from packed arrays (L2-resident), 2 banks, 2-chunk lead.
// 4 waves/SIMD (vs 2 in prior rounds): doubles TLP at identical global/L2/MFMA traffic.
__global__ __launch_bounds__(1024, 1)
void gmm_fused(const float* __restrict__ x,
               const _Float16* __restrict__ Upk,
               const _Float16* __restrict__ Wpk,
               const float* __restrict__ ecg,
               float* __restrict__ out) {
    __shared__ __align__(16) char xlds[65536];  // 4 quarters x [32 rows][256 dims] f16, XOR-swizzled
    __shared__ float red[16][32];

    const int tid = threadIdx.x;
    const int wave = tid >> 6, lane = tid & 63;
    const int l15 = lane & 15, g4 = lane >> 4;
    const int bRow = blockIdx.x * 32;

    // staging: thread -> row = tid>>5 (0..31); 8 dims at (tid&31)*8 within each 256-dim quarter
    const int srow = tid >> 5, sd = (tid & 31) * 8;
    const float* xq = x + (size_t)(bRow + srow) * DIM_N + sd;
    const int wByte = srow * 512 + ((((sd >> 3) ^ (srow & 7)) << 4));

    // B packed base: wave's class-group cg = wave
    const _Float16* upb = Upk + (size_t)wave * 32 * 512 + lane * 8;
    const _Float16* wpb = Wpk + (size_t)wave * 32 * 512 + lane * 8;

    f32x4 acc[2];
#pragma unroll
    for (int m = 0; m < 2; ++m) { f32x4 z = {0.f, 0.f, 0.f, 0.f}; acc[m] = z; }

    float4 xs[2][2];           // staging regs, 2 quarter-banks x 2 float4
    f16x8 ub[2][2], wb[2][2];  // [bank][k2]

    auto issueQ = [&](int bank, int q) {
        xs[bank][0] = *(const float4*)(xq + q * 256);
        xs[bank][1] = *(const float4*)(xq + q * 256 + 4);
    };
    auto writeQ = [&](int bank, int q) {
        const float4 a = xs[bank][0], b = xs[bank][1];
        f16x8 h = {(_Float16)a.x, (_Float16)a.y, (_Float16)a.z, (_Float16)a.w,
                   (_Float16)b.x, (_Float16)b.y, (_Float16)b.z, (_Float16)b.w};
        *(f16x8*)(xlds + q * 16384 + wByte) = h;
    };
    auto issueB = [&](int bank, int c) {
#pragma unroll
        for (int k2 = 0; k2 < 2; ++k2) {
            const int kc = c * 2 + k2;
            ub[bank][k2] = *(const f16x8*)(upb + (size_t)kc * 512);
            wb[bank][k2] = *(const f16x8*)(wpb + (size_t)kc * 512);
        }
    };
    auto compute = [&](int c, int bank) {
        const char* base = xlds + (c >> 2) * 16384;
        const int cl = c & 3;
        f16x8 axf[2][2];
#pragma unroll
        for (int m = 0; m < 2; ++m)
#pragma unroll
            for (int k2 = 0; k2 < 2; ++k2) {
                const int row = m * 16 + l15;
                const int slot = cl * 8 + k2 * 4 + g4;
                axf[m][k2] = *(const f16x8*)(base + row * 512 + ((slot ^ (l15 & 7)) << 4));
            }
        __builtin_amdgcn_s_setprio(1);
#pragma unroll
        for (int m = 0; m < 2; ++m)
#pragma unroll
            for (int k2 = 0; k2 < 2; ++k2) {
                const f16x8 a2 = axf[m][k2] * axf[m][k2];   // x^2 in-register (v_pk_mul_f16)
                acc[m] = __builtin_amdgcn_mfma_f32_16x16x32_f16(a2, ub[bank][k2], acc[m], 0, 0, 0);
                acc[m] = __builtin_amdgcn_mfma_f32_16x16x32_f16(axf[m][k2], wb[bank][k2], acc[m], 0, 0, 0);
            }
        __builtin_amdgcn_s_setprio(0);
    };

    // ---- staging pipeline + K-loop: 4 barriers total ----
    issueB(0, 0); issueB(1, 1);
    issueQ(0, 0); issueQ(1, 1);
    writeQ(0, 0);
    issueQ(0, 2);
    asm volatile("s_waitcnt lgkmcnt(0)" ::: "memory");
    __builtin_amdgcn_s_barrier();              // quarter 0 ready
    __builtin_amdgcn_sched_barrier(0);
    writeQ(1, 1);
    issueQ(1, 3);
    compute(0, 0); issueB(0, 2);
    compute(1, 1); issueB(1, 3);
    compute(2, 0); issueB(0, 4);
    compute(3, 1); issueB(1, 5);
    asm volatile("s_waitcnt lgkmcnt(0)" ::: "memory");
    __builtin_amdgcn_s_barrier();              // quarter 1 ready
    __builtin_amdgcn_sched_barrier(0);
    writeQ(0, 2);
    compute(4, 0); issueB(0, 6);
    compute(5, 1); issueB(1, 7);
    compute(6, 0); issueB(0, 8);
    compute(7, 1); issueB(1, 9);
    asm volatile("s_waitcnt lgkmcnt(0)" ::: "memory");
    __builtin_amdgcn_s_barrier();              // quarter 2 ready
    __builtin_amdgcn_sched_barrier(0);
    writeQ(1, 3);
    compute(8, 0);  issueB(0, 10);
    compute(9, 1);  issueB(1, 11);
    compute(10, 0); issueB(0, 12);
    compute(11, 1); issueB(1, 13);
    asm volatile("s_waitcnt lgkmcnt(0)" ::: "memory");
    __builtin_amdgcn_s_barrier();              // quarter 3 ready
    __builtin_amdgcn_sched_barrier(0);
    compute(12, 0); issueB(0, 14);
    compute(13, 1); issueB(1, 15);
    compute(14, 0);
    compute(15, 1);

    // ---- fused epilogue: e = -0.5*acc + ec[k]; weighted row softmax across 16 waves ----
    const int cls0 = wave * 16 + l15;
    const float ecv = ecg[cls0];

    float e[2][4];
#pragma unroll
    for (int m = 0; m < 2; ++m)
#pragma unroll
        for (int j = 0; j < 4; ++j)
            e[m][j] = fmaf(-0.5f, acc[m][j], ecv);

    float mx[2][4];
#pragma unroll
    for (int m = 0; m < 2; ++m)
#pragma unroll
        for (int j = 0; j < 4; ++j) mx[m][j] = e[m][j];
#pragma unroll
    for (int msk = 1; msk <= 8; msk <<= 1)
#pragma unroll
        for (int m = 0; m < 2; ++m)
#pragma unroll
            for (int j = 0; j < 4; ++j)
                mx[m][j] = fmaxf(mx[m][j], __shfl_xor(mx[m][j], msk, 64));
    if (l15 == 0) {
#pragma unroll
        for (int m = 0; m < 2; ++m)
#pragma unroll
            for (int j = 0; j < 4; ++j) red[wave][m * 16 + g4 * 4 + j] = mx[m][j];
    }
    __syncthreads();
    float gm[2][4];
#pragma unroll
    for (int m = 0; m < 2; ++m)
#pragma unroll
        for (int j = 0; j < 4; ++j) {
            const int r = m * 16 + g4 * 4 + j;
            float v = red[0][r];
#pragma unroll
            for (int w = 1; w < 16; ++w) v = fmaxf(v, red[w][r]);
            gm[m][j] = v;
        }
    __syncthreads();

    float p2[2][4], sm[2][4];
#pragma unroll
    for (int m = 0; m < 2; ++m)
#pragma unroll
        for (int j = 0; j < 4; ++j) {
            p2[m][j] = __expf(e[m][j] - gm[m][j]);
            sm[m][j] = p2[m][j];
        }
#pragma unroll
    for (int msk = 1; msk <= 8; msk <<= 1)
#pragma unroll
        for (int m = 0; m < 2; ++m)
#pragma unroll
            for (int j = 0; j < 4; ++j) sm[m][j] += __shfl_xor(sm[m][j], msk, 64);
    if (l15 == 0) {
#pragma unroll
        for (int m = 0; m < 2; ++m)
#pragma unroll
            for (int j = 0; j < 4; ++j) red[wave][m * 16 + g4 * 4 + j] = sm[m][j];
    }
    __syncthreads();
#pragma unroll
    for (int m = 0; m < 2; ++m)
#pragma unroll
        for (int j = 0; j < 4; ++j) {
            const int r = m * 16 + g4 * 4 + j;
            float t = red[0][r];
#pragma unroll
            for (int w = 1; w < 16; ++w) t += red[w][r];
            out[(size_t)(bRow + r) * K_N + cls0] = p2[m][j] / t;
        }
}

extern "C" void kernel_launch(void* const* d_in, const int* in_sizes, int n_in,
                              void* d_out, int out_size, void* d_ws, size_t ws_size,
                              hipStream_t stream) {
    const float* x = (const float*)d_in[0];
    const float* cen = (const float*)d_in[1];
    const float* Dm = (const float*)d_in[2];
    float* out = (float*)d_out;

    char* ws = (char*)d_ws;
    _Float16* Upk = (_Float16*)(ws);                // 512 KB packed
    _Float16* Wpk = (_Float16*)(ws + 524288);       // 512 KB packed
    float* ec = (float*)(ws + 1048576);             // 1 KB

    prep_w<<<dim3(K_N), dim3(256), 0, stream>>>(Dm, cen, Upk, Wpk, ec);
    gmm_fused<<<dim3(B_N / 32), dim3(1024), 0, stream>>>(x, Upk, Wpk, ec, out);
}

// Round 12
// 30.889 us; speedup vs baseline: 1.0606x; 1.0606x over previous
//
#include <hip/hip_runtime.h>

typedef _Float16 f16x8 __attribute__((ext_vector_type(8)));
typedef _Float16 f16x4 __attribute__((ext_vector_type(4)));
typedef float f32x4 __attribute__((ext_vector_type(4)));

#define B_N 8192
#define K_N 256
#define DIM_N 1024

// ---------------- prep_w: U=f16(Dinv-1), W=f16(-2c*Dinv) in MFMA-fragment-PACKED layout ----------------
// pk f16-index: ((cg*32 + kc)*64 + g*16 + cl)*8 + j  where class k=(cg*16+cl), dim d=(kc*32+g*8+j).
// A wave reading pk + (cg*32+kc)*512 + lane*8 gets exactly the B-fragment (col=lane&15, k=(lane>>4)*8+j).
// ec[k] = -0.5*(log_det + c2): softmax_k(-0.5*acc + ec) == reference resp (row-consts cancel).
__global__ __launch_bounds__(256) void prep_w(const float* __restrict__ Dm,
                                              const float* __restrict__ Cm,
                                              _Float16* __restrict__ Upk,
                                              _Float16* __restrict__ Wpk,
                                              float* __restrict__ ec) {
    const int k = blockIdx.x, t = threadIdx.x;
    const int d = t * 4;
    const float4 dv = *(const float4*)(Dm + (size_t)k * DIM_N + d);
    const float4 cv = *(const float4*)(Cm + (size_t)k * DIM_N + d);
    float dd[4] = {dv.x, dv.y, dv.z, dv.w};
    float cc[4] = {cv.x, cv.y, cv.z, cv.w};
    f16x4 uo, wo;
    float llog = 0.f, lc2 = 0.f;
#pragma unroll
    for (int i = 0; i < 4; ++i) {
        float da = fabsf(dd[i]) + 1e-4f;
        float dinv = 1.0f / da;
        llog += logf(da);
        lc2 += cc[i] * cc[i] * dinv;
        uo[i] = (_Float16)(dinv - 1.0f);
        wo[i] = (_Float16)(-2.0f * cc[i] * dinv);
    }
    const int cg = k >> 4, cl = k & 15;
    const int kc = d >> 5, g = (d >> 3) & 3, j0 = d & 7;
    const size_t off = ((size_t)(cg * 32 + kc) * 64 + g * 16 + cl) * 8 + j0;
    *(f16x4*)(Upk + off) = uo;
    *(f16x4*)(Wpk + off) = wo;
    float both = llog + lc2;
#pragma unroll
    for (int m = 1; m <= 32; m <<= 1) both += __shfl_xor(both, m, 64);
    __shared__ float sb[4];
    if ((t & 63) == 0) sb[t >> 6] = both;
    __syncthreads();
    if (t == 0) ec[k] = -0.5f * (sb[0] + sb[1] + sb[2] + sb[3]);
}

// ---------------- gmm_fused: 32 rows x 256 classes; A fragment-packed in LDS, 3-bank B stream ----------------
// 8 waves (512 thr), wave w owns classes w*32..w*32+31 (m2 n2, 2 products, 16 MFMA/chunk-64).
// A LDS layout: chunk c tile at c*4096; frag(m,k2) at (m*2+k2)*1024 + lane*16 -> stride-1 reads,
// permutation-of-contiguous writes: conflict-free BY CONSTRUCTION (no swizzle). x^2 in-register.
// B (U,W): register fragments from packed arrays (L2-resident), 3 banks = 3-chunk lead (~300+ cy).
// x staged ONCE (4 quarters of 16KB, 4 raw barriers; only lgkmcnt drained, vmem stays in flight).
__global__ __launch_bounds__(512, 1)
void gmm_fused(const float* __restrict__ x,
               const _Float16* __restrict__ Upk,
               const _Float16* __restrict__ Wpk,
               const float* __restrict__ ecg,
               float* __restrict__ out) {
    __shared__ __align__(16) char xlds[65536];  // 16 chunk-tiles x 4KB, fragment-packed
    __shared__ float red[8][32];

    const int tid = threadIdx.x;
    const int wave = tid >> 6, lane = tid & 63;
    const int l15 = lane & 15, g4 = lane >> 4;
    const int bRow = blockIdx.x * 32;

    // staging: thread -> row srow = tid>>4 (0..31), 16 dims at (tid&15)*16 within each 256-dim quarter
    const int srow = tid >> 4, sdq = tid & 15;
    const float* xq = x + (size_t)(bRow + srow) * DIM_N + sdq * 16;
    // fragment-packed write offset (within a quarter's 16KB):
    const int smq = srow >> 4, r15 = srow & 15;
    const int scl = sdq >> 2;                 // chunk within quarter
    const int dc0 = (sdq & 3) * 16;           // dim offset within chunk
    const int sk2 = dc0 >> 5, sgb = (dc0 >> 3) & 3;
    const int wOff = scl * 4096 + (smq * 2 + sk2) * 1024 + (r15 + sgb * 16) * 16;

    // B packed bases: wave's class-groups cg = wave*2 + n
    const _Float16* upb = Upk + (size_t)(wave * 2) * 32 * 512 + lane * 8;
    const _Float16* wpb = Wpk + (size_t)(wave * 2) * 32 * 512 + lane * 8;

    f32x4 acc[2][2];
#pragma unroll
    for (int m = 0; m < 2; ++m)
#pragma unroll
        for (int n = 0; n < 2; ++n) { f32x4 z = {0.f, 0.f, 0.f, 0.f}; acc[m][n] = z; }

    float4 xs[2][4];                 // staging regs: 2 quarter-banks x 16 floats
    f16x8 ub[3][2][2], wb[3][2][2];  // [bank][n][k2], 3-chunk lead

    auto issueQ = [&](int bank, int q) {
#pragma unroll
        for (int j = 0; j < 4; ++j) xs[bank][j] = *(const float4*)(xq + q * 256 + j * 4);
    };
    auto writeQ = [&](int bank, int q) {
        const float4 a = xs[bank][0], b = xs[bank][1], c = xs[bank][2], d = xs[bank][3];
        f16x8 h0 = {(_Float16)a.x, (_Float16)a.y, (_Float16)a.z, (_Float16)a.w,
                    (_Float16)b.x, (_Float16)b.y, (_Float16)b.z, (_Float16)b.w};
        f16x8 h1 = {(_Float16)c.x, (_Float16)c.y, (_Float16)c.z, (_Float16)c.w,
                    (_Float16)d.x, (_Float16)d.y, (_Float16)d.z, (_Float16)d.w};
        *(f16x8*)(xlds + q * 16384 + wOff) = h0;
        *(f16x8*)(xlds + q * 16384 + wOff + 256) = h1;   // next 8-dim group = +16 lanes
    };
    auto issueB = [&](int bank, int c) {
#pragma unroll
        for (int n = 0; n < 2; ++n)
#pragma unroll
            for (int k2 = 0; k2 < 2; ++k2) {
                const int kc = c * 2 + k2;
                ub[bank][n][k2] = *(const f16x8*)(upb + (size_t)(n * 32 + kc) * 512);
                wb[bank][n][k2] = *(const f16x8*)(wpb + (size_t)(n * 32 + kc) * 512);
            }
    };
    auto compute = [&](int c, int bank) {
        const char* base = xlds + c * 4096;
        f16x8 axf[2][2];
#pragma unroll
        for (int m = 0; m < 2; ++m)
#pragma unroll
            for (int k2 = 0; k2 < 2; ++k2)
                axf[m][k2] = *(const f16x8*)(base + (m * 2 + k2) * 1024 + lane * 16);
#pragma unroll
        for (int m = 0; m < 2; ++m)
#pragma unroll
            for (int k2 = 0; k2 < 2; ++k2) {
                const f16x8 a2 = axf[m][k2] * axf[m][k2];   // x^2 in-register
#pragma unroll
                for (int n = 0; n < 2; ++n) {
                    acc[m][n] = __builtin_amdgcn_mfma_f32_16x16x32_f16(a2, ub[bank][n][k2], acc[m][n], 0, 0, 0);
                    acc[m][n] = __builtin_amdgcn_mfma_f32_16x16x32_f16(axf[m][k2], wb[bank][n][k2], acc[m][n], 0, 0, 0);
                }
            }
    };

    // ---- prologue: B chunks 0-2 + x quarters 0,1 in flight; stage quarter 0 ----
    issueB(0, 0); issueB(1, 1); issueB(2, 2);
    issueQ(0, 0); issueQ(1, 1);
    writeQ(0, 0);
    issueQ(0, 2);
    asm volatile("s_waitcnt lgkmcnt(0)" ::: "memory");
    __builtin_amdgcn_s_barrier();              // quarter 0 ready
    __builtin_amdgcn_sched_barrier(0);
    writeQ(1, 1);
    issueQ(1, 3);
    compute(0, 0);  issueB(0, 3);
    compute(1, 1);  issueB(1, 4);
    compute(2, 2);  issueB(2, 5);
    compute(3, 0);  issueB(0, 6);
    asm volatile("s_waitcnt lgkmcnt(0)" ::: "memory");
    __builtin_amdgcn_s_barrier();              // quarter 1 ready
    __builtin_amdgcn_sched_barrier(0);
    writeQ(0, 2);
    compute(4, 1);  issueB(1, 7);
    compute(5, 2);  issueB(2, 8);
    compute(6, 0);  issueB(0, 9);
    compute(7, 1);  issueB(1, 10);
    asm volatile("s_waitcnt lgkmcnt(0)" ::: "memory");
    __builtin_amdgcn_s_barrier();              // quarter 2 ready
    __builtin_amdgcn_sched_barrier(0);
    writeQ(1, 3);
    compute(8, 2);   issueB(2, 11);
    compute(9, 0);   issueB(0, 12);
    compute(10, 1);  issueB(1, 13);
    compute(11, 2);  issueB(2, 14);
    asm volatile("s_waitcnt lgkmcnt(0)" ::: "memory");
    __builtin_amdgcn_s_barrier();              // quarter 3 ready
    __builtin_amdgcn_sched_barrier(0);
    compute(12, 0);  issueB(0, 15);
    compute(13, 1);
    compute(14, 2);
    compute(15, 0);

    // ---- fused epilogue: e = -0.5*acc + ec[k]; weighted row softmax across waves ----
    const int cls0 = wave * 32 + l15;
    const float ecv[2] = {ecg[cls0], ecg[cls0 + 16]};

    float e[2][2][4];
#pragma unroll
    for (int m = 0; m < 2; ++m)
#pragma unroll
        for (int n = 0; n < 2; ++n)
#pragma unroll
            for (int j = 0; j < 4; ++j)
                e[m][n][j] = fmaf(-0.5f, acc[m][n][j], ecv[n]);

    float mx[2][4];
#pragma unroll
    for (int m = 0; m < 2; ++m)
#pragma unroll
        for (int j = 0; j < 4; ++j) mx[m][j] = fmaxf(e[m][0][j], e[m][1][j]);
#pragma unroll
    for (int msk = 1; msk <= 8; msk <<= 1)
#pragma unroll
        for (int m = 0; m < 2; ++m)
#pragma unroll
            for (int j = 0; j < 4; ++j)
                mx[m][j] = fmaxf(mx[m][j], __shfl_xor(mx[m][j], msk, 64));
    if (l15 == 0) {
#pragma unroll
        for (int m = 0; m < 2; ++m)
#pragma unroll
            for (int j = 0; j < 4; ++j) red[wave][m * 16 + g4 * 4 + j] = mx[m][j];
    }
    __syncthreads();
    float gm[2][4];
#pragma unroll
    for (int m = 0; m < 2; ++m)
#pragma unroll
        for (int j = 0; j < 4; ++j) {
            const int r = m * 16 + g4 * 4 + j;
            float v = red[0][r];
#pragma unroll
            for (int w = 1; w < 8; ++w) v = fmaxf(v, red[w][r]);
            gm[m][j] = v;
        }
    __syncthreads();

    float p2[2][2][4], sfs[2][4];
#pragma unroll
    for (int m = 0; m < 2; ++m)
#pragma unroll
        for (int j = 0; j < 4; ++j) sfs[m][j] = 0.f;
#pragma unroll
    for (int m = 0; m < 2; ++m)
#pragma unroll
        for (int n = 0; n < 2; ++n)
#pragma unroll
            for (int j = 0; j < 4; ++j) {
                p2[m][n][j] = __expf(e[m][n][j] - gm[m][j]);
                sfs[m][j] += p2[m][n][j];
            }
#pragma unroll
    for (int msk = 1; msk <= 8; msk <<= 1)
#pragma unroll
        for (int m = 0; m < 2; ++m)
#pragma unroll
            for (int j = 0; j < 4; ++j) sfs[m][j] += __shfl_xor(sfs[m][j], msk, 64);
    if (l15 == 0) {
#pragma unroll
        for (int m = 0; m < 2; ++m)
#pragma unroll
            for (int j = 0; j < 4; ++j) red[wave][m * 16 + g4 * 4 + j] = sfs[m][j];
    }
    __syncthreads();
#pragma unroll
    for (int m = 0; m < 2; ++m)
#pragma unroll
        for (int j = 0; j < 4; ++j) {
            const int r = m * 16 + g4 * 4 + j;
            float t = red[0][r];
#pragma unroll
            for (int w = 1; w < 8; ++w) t += red[w][r];
            const float inv = 1.0f / t;
#pragma unroll
            for (int n = 0; n < 2; ++n)
                out[(size_t)(bRow + r) * K_N + cls0 + n * 16] = p2[m][n][j] * inv;
        }
}

extern "C" void kernel_launch(void* const* d_in, const int* in_sizes, int n_in,
                              void* d_out, int out_size, void* d_ws, size_t ws_size,
                              hipStream_t stream) {
    const float* x = (const float*)d_in[0];
    const float* cen = (const float*)d_in[1];
    const float* Dm = (const float*)d_in[2];
    float* out = (float*)d_out;

    char* ws = (char*)d_ws;
    _Float16* Upk = (_Float16*)(ws);                // 512 KB packed
    _Float16* Wpk = (_Float16*)(ws + 524288);       // 512 KB packed
    float* ec = (float*)(ws + 1048576);             // 1 KB

    prep_w<<<dim3(K_N), dim3(256), 0, stream>>>(Dm, cen, Upk, Wpk, ec);
    gmm_fused<<<dim3(B_N / 32), dim3(512), 0, stream>>>(x, Upk, Wpk, ec, out);
}